// Round 6
// baseline (315.046 us; speedup 1.0000x reference)
//
#include <hip/hip_runtime.h>
#include <hip/hip_bf16.h>
#include <hip/hip_cooperative_groups.h>
#include <math.h>

// Problem constants (match reference)
#define BB 2
#define LL 4096
#define DD 128
#define ED 256
#define NN 16
#define KK 4
#define RR 8
#define HH 256
#define NT (BB*LL)          // 8192 tokens
#define NC 128              // chunks for scan
#define LC 32               // chunk length (NC*LC == LL)

typedef __attribute__((ext_vector_type(8))) short short8;
typedef __attribute__((ext_vector_type(8))) unsigned short ushort8v;
typedef __attribute__((ext_vector_type(4))) float floatx4;

__device__ __forceinline__ unsigned short f2bf(float f) {
  unsigned int b = __builtin_bit_cast(unsigned int, f);
  b += 0x7FFFu + ((b >> 16) & 1u);           // round-to-nearest-even
  return (unsigned short)(b >> 16);
}

// ---------------------------------------------------------------------------
// One-shot fp32->bf16 conversion of the 5 weight matrices used by MFMA paths.
// float4 units: in_w 16384 | out_w 8192 | fc1 8192 | fc2 8192 | xproj 2560
// ---------------------------------------------------------------------------
__global__ __launch_bounds__(256) void cvt5_k(const float* __restrict__ a,
    const float* __restrict__ b, const float* __restrict__ c,
    const float* __restrict__ d, const float* __restrict__ e5,
    unsigned short* __restrict__ oa, unsigned short* __restrict__ ob,
    unsigned short* __restrict__ oc, unsigned short* __restrict__ od,
    unsigned short* __restrict__ oe) {
  const int i = blockIdx.x*256 + threadIdx.x;   // < 43520 float4s
  const float* src; unsigned short* dst; int off;
  if (i < 16384)      { src = a;  dst = oa; off = i; }
  else if (i < 24576) { src = b;  dst = ob; off = i - 16384; }
  else if (i < 32768) { src = c;  dst = oc; off = i - 24576; }
  else if (i < 40960) { src = d;  dst = od; off = i - 32768; }
  else                { src = e5; dst = oe; off = i - 40960; }
  const float4 v = ((const float4*)src)[off];
  unsigned int lo = f2bf(v.x) | ((unsigned int)f2bf(v.y) << 16);
  unsigned int hi = f2bf(v.z) | ((unsigned int)f2bf(v.w) << 16);
  ((uint2*)dst)[off] = make_uint2(lo, hi);
}

// ---------------------------------------------------------------------------
// LayerNorm, wave-per-token, bf16 output (feeds GEMM A-operand only).
// ---------------------------------------------------------------------------
template<bool DOUBLE>
__global__ __launch_bounds__(256) void ln2_k(const float* __restrict__ x,
    const float* __restrict__ g1, const float* __restrict__ b1,
    const float* __restrict__ g2, const float* __restrict__ b2,
    unsigned short* __restrict__ out) {
  const int token = blockIdx.x*4 + (threadIdx.x >> 6);
  const int lane  = threadIdx.x & 63;
  float2 v = *(const float2*)(x + (size_t)token*DD + lane*2);

  auto wsum = [&](float s) -> float {
    s += __shfl_xor(s, 32); s += __shfl_xor(s, 16); s += __shfl_xor(s, 8);
    s += __shfl_xor(s, 4);  s += __shfl_xor(s, 2);  s += __shfl_xor(s, 1);
    return s;
  };

  float mean = wsum(v.x + v.y) * (1.f/128.f);
  float cx = v.x - mean, cy = v.y - mean;
  float var = wsum(cx*cx + cy*cy) * (1.f/128.f);
  float rs = rsqrtf(var + 1e-5f);
  const float2 g = *(const float2*)(g1 + lane*2);
  const float2 bb = *(const float2*)(b1 + lane*2);
  float yx = cx*rs*g.x + bb.x;
  float yy = cy*rs*g.y + bb.y;
  if constexpr (DOUBLE) {
    float m2 = wsum(yx + yy) * (1.f/128.f);
    float c2x = yx - m2, c2y = yy - m2;
    float v2 = wsum(c2x*c2x + c2y*c2y) * (1.f/128.f);
    float rs2 = rsqrtf(v2 + 1e-5f);
    const float2 g2v = *(const float2*)(g2 + lane*2);
    const float2 b2v = *(const float2*)(b2 + lane*2);
    yx = c2x*rs2*g2v.x + b2v.x;
    yy = c2y*rs2*g2v.y + b2v.y;
  }
  const unsigned int packed = f2bf(yx) | ((unsigned int)f2bf(yy) << 16);
  *(unsigned int*)(out + (size_t)token*DD + lane*2) = packed;
}

// ---------------------------------------------------------------------------
// bf16 MFMA GEMM: C[M,Nn] = A[M,KD] @ W[Nn,KD]^T; A,W pre-converted bf16.
// 64x64 tile, 4 waves (2x2 of 32x32), 16x16x32 fragments.
// EPI: 0 = none; 1 = +res; 2 = gelu(+bias); 3 = +bias +res
// ---------------------------------------------------------------------------
template<int KD, int EPI, typename OT>
__global__ __launch_bounds__(256) void gemm_bf_k(
    const unsigned short* __restrict__ A, const unsigned short* __restrict__ W,
    const float* __restrict__ bias, const float* __restrict__ res,
    OT* __restrict__ C, int Nn) {
  static_assert(KD % 128 == 0, "KD multiple of 128");
  __shared__ unsigned short As[64][136];   // 64 rows x 128 bf16, pad 8
  __shared__ unsigned short Ws[64][136];

  const int row0 = blockIdx.y * 64;
  const int col0 = blockIdx.x * 64;
  const int tid  = threadIdx.x;
  const int wave = tid >> 6;
  const int lane = tid & 63;
  const int quad = lane >> 4;
  const int l16  = lane & 15;
  const int wm = (wave & 1) * 32;
  const int wn = (wave >> 1) * 32;
  const int lr = tid >> 2;            // staging row 0..63
  const int lc = (tid & 3) * 32;      // staging col (32 bf16 = 64 B)

  floatx4 acc[2][2] = {};

  for (int ks0 = 0; ks0 < KD; ks0 += 128) {
    const unsigned short* Ap = A + (size_t)(row0 + lr)*KD + ks0 + lc;
    const unsigned short* Wp = W + (size_t)(col0 + lr)*KD + ks0 + lc;
    ushort8v av[4], wv[4];
    #pragma unroll
    for (int g = 0; g < 4; g++) {
      av[g] = *(const ushort8v*)(Ap + g*8);
      wv[g] = *(const ushort8v*)(Wp + g*8);
    }
    __syncthreads();
    #pragma unroll
    for (int g = 0; g < 4; g++) {
      *(ushort8v*)&As[lr][lc + g*8] = av[g];
      *(ushort8v*)&Ws[lr][lc + g*8] = wv[g];
    }
    __syncthreads();
    #pragma unroll
    for (int ks = 0; ks < 4; ks++) {
      const int ko = ks*32 + quad*8;
      short8 a0 = *(const short8*)&As[wm +      l16][ko];
      short8 a1 = *(const short8*)&As[wm + 16 + l16][ko];
      short8 b0 = *(const short8*)&Ws[wn +      l16][ko];
      short8 b1 = *(const short8*)&Ws[wn + 16 + l16][ko];
      acc[0][0] = __builtin_amdgcn_mfma_f32_16x16x32_bf16(a0, b0, acc[0][0], 0, 0, 0);
      acc[0][1] = __builtin_amdgcn_mfma_f32_16x16x32_bf16(a0, b1, acc[0][1], 0, 0, 0);
      acc[1][0] = __builtin_amdgcn_mfma_f32_16x16x32_bf16(a1, b0, acc[1][0], 0, 0, 0);
      acc[1][1] = __builtin_amdgcn_mfma_f32_16x16x32_bf16(a1, b1, acc[1][1], 0, 0, 0);
    }
  }

  #pragma unroll
  for (int i = 0; i < 2; i++) {
    #pragma unroll
    for (int j = 0; j < 2; j++) {
      const int n = col0 + wn + j*16 + l16;
      float bn = 0.f;
      if constexpr (EPI == 2 || EPI == 3) bn = bias[n];
      #pragma unroll
      for (int r = 0; r < 4; r++) {
        const int m = row0 + wm + i*16 + quad*4 + r;
        float v = acc[i][j][r];
        if constexpr (EPI == 2 || EPI == 3) v += bn;
        if constexpr (EPI == 2) v = 0.5f*v*(1.f + erff(v*0.70710678118f));
        const size_t o = (size_t)m*Nn + n;
        if constexpr (EPI == 1 || EPI == 3) v += res[o];
        if constexpr (sizeof(OT) == 2) C[o] = (OT)f2bf(v);
        else                           C[o] = v;
      }
    }
  }
}

// ---------------------------------------------------------------------------
// Cooperative SSM core: conv+silu -> xproj(MFMA) -> delta -> chunked scan ->
// gate, all in one kernel with two grid.sync()s. 512 blocks (2/CU resident,
// LDS 70.5 KB/block), block = (b, chunk c of 32 tokens, e-half of 128 ch).
// Conv/xproj duplicated across the two e-half blocks of a chunk (cheap);
// u/dt/B/C/delta all stay in LDS. Only chunk summaries (cA/cH, 2 MB) cross
// blocks, bridged by grid sync. Scan thread owns (e, n-half): h[8] in regs.
// ---------------------------------------------------------------------------
__global__ __launch_bounds__(256) void mamba_core_k(
    const float* __restrict__ xz, const float* __restrict__ cw,
    const float* __restrict__ cb, const unsigned short* __restrict__ xpwb,
    const float* __restrict__ dtw, const float* __restrict__ dtb,
    const float* __restrict__ A_log, const float* __restrict__ Dpv,
    float* __restrict__ cA, float* __restrict__ cH,
    unsigned short* __restrict__ ybf) {
  namespace cg = cooperative_groups;
  cg::grid_group grid = cg::this_grid();

  __shared__ __align__(16) unsigned short Bs[64][264];  // xproj W (40 real rows)
  __shared__ __align__(16) unsigned short As[32][264];  // u-tile bf16 (A-layout)
  __shared__ float su[32][128];                         // u fp32, own e-half
  __shared__ float sdbc[32][40];                        // dt|B|C per token
  float (*sdel)[128] = reinterpret_cast<float(*)[128]>(&As[0][0]); // aliases As

  const int gid = blockIdx.x;
  const int eb = gid & 1;           // e-half
  const int b  = (gid >> 1) & 1;    // batch
  const int c  = gid >> 2;          // chunk
  const int tid = threadIdx.x;
  const int t0 = b*LL + c*LC;       // global token base of chunk

  // --- stage xproj weights (coalesced; rows >= 40 zeroed) ---
  #pragma unroll
  for (int p = 0; p < 8; p++) {
    const int idx = p*256 + tid;           // 2048 chunks of 8 shorts
    const int row = idx >> 5;
    const int col = (idx & 31) * 8;
    ushort8v v = {};
    if (row < 40) v = *(const ushort8v*)(xpwb + row*ED + col);
    *(ushort8v*)&Bs[row][col] = v;
  }

  // --- conv: rolling window, channel ch = tid (all 256 channels) ---
  {
    const int ch = tid;
    const float4 w = *(const float4*)(cw + ch*4);
    const float cbe = cb[ch];
    float h0 = 0.f, h1 = 0.f, h2 = 0.f;
    if (c != 0) {
      h0 = xz[(size_t)(t0-3)*(2*ED) + ch];
      h1 = xz[(size_t)(t0-2)*(2*ED) + ch];
      h2 = xz[(size_t)(t0-1)*(2*ED) + ch];
    }
    const bool own = (ch >> 7) == eb;
    #pragma unroll 8
    for (int i = 0; i < LC; i++) {
      const float cur = xz[(size_t)(t0+i)*(2*ED) + ch];
      const float a = cbe + h0*w.x + h1*w.y + h2*w.z + cur*w.w;
      const float s = a / (1.f + __expf(-a));
      As[i][ch] = f2bf(s);
      if (own) su[i][ch & 127] = s;
      h0 = h1; h1 = h2; h2 = cur;
    }
  }
  __syncthreads();

  // --- xproj MFMA: M=32 (2 m-frags), N=64 (4 n-frags), K=256 ---
  const int wave = tid >> 6, lane = tid & 63;
  const int quad = lane >> 4, l16 = lane & 15;
  {
    const int mi = (wave & 1) * 16;
    const int j0 = (wave >> 1) * 2;
    floatx4 acc[2] = {};
    #pragma unroll
    for (int ks = 0; ks < 8; ks++) {
      const int ko = ks*32 + quad*8;
      short8 a  = *(const short8*)&As[mi + l16][ko];
      short8 b0 = *(const short8*)&Bs[j0*16 +      l16][ko];
      short8 b1 = *(const short8*)&Bs[j0*16 + 16 + l16][ko];
      acc[0] = __builtin_amdgcn_mfma_f32_16x16x32_bf16(a, b0, acc[0], 0, 0, 0);
      acc[1] = __builtin_amdgcn_mfma_f32_16x16x32_bf16(a, b1, acc[1], 0, 0, 0);
    }
    __syncthreads();   // all As/Bs reads done before sdel aliases As
    #pragma unroll
    for (int f = 0; f < 2; f++) {
      const int n = (j0 + f)*16 + l16;
      #pragma unroll
      for (int r = 0; r < 4; r++) {
        const int m = mi + quad*4 + r;
        if (n < 40) sdbc[m][n] = acc[f][r];
      }
    }
  }
  __syncthreads();

  // --- delta: softplus(dt @ dt_w^T + dt_b) for own 128 channels ---
  const int e_loc = tid >> 1;
  const int half  = tid & 1;
  const int e     = eb*128 + e_loc;
  {
    const float4 w0 = *(const float4*)(dtw + e*RR);
    const float4 w1 = *(const float4*)(dtw + e*RR + 4);
    const float db = dtb[e];
    #pragma unroll 4
    for (int i = 0; i < 16; i++) {
      const int t = half*16 + i;
      const float a = db
          + sdbc[t][0]*w0.x + sdbc[t][1]*w0.y + sdbc[t][2]*w0.z + sdbc[t][3]*w0.w
          + sdbc[t][4]*w1.x + sdbc[t][5]*w1.y + sdbc[t][6]*w1.z + sdbc[t][7]*w1.w;
      sdel[t][e_loc] = (a > 20.f) ? a : log1pf(__expf(a));
    }
  }
  __syncthreads();

  // --- scan phase 1: per-chunk (prodA, h_end); thread owns (e, n-half) ---
  const int n0 = half * 8;
  const float4 a0 = *(const float4*)(A_log + e*NN + n0);
  const float4 a1 = *(const float4*)(A_log + e*NN + n0 + 4);
  float Aen[8] = {-__expf(a0.x), -__expf(a0.y), -__expf(a0.z), -__expf(a0.w),
                  -__expf(a1.x), -__expf(a1.y), -__expf(a1.z), -__expf(a1.w)};
  const size_t base = (((size_t)c*BB + b)*ED + e)*NN + n0;
  {
    float h[8] = {};
    float sumd = 0.f;
    for (int i = 0; i < LC; i++) {
      const float dv = sdel[i][e_loc];
      const float du = dv * su[i][e_loc];
      const float4 B0 = *(const float4*)&sdbc[i][RR + n0];
      const float4 B1 = *(const float4*)&sdbc[i][RR + n0 + 4];
      const float Bv[8] = {B0.x,B0.y,B0.z,B0.w,B1.x,B1.y,B1.z,B1.w};
      sumd += dv;
      #pragma unroll
      for (int j = 0; j < 8; j++)
        h[j] = __expf(dv * Aen[j])*h[j] + Bv[j]*du;
    }
    *(float4*)(cA + base)     = make_float4(__expf(sumd*Aen[0]), __expf(sumd*Aen[1]),
                                            __expf(sumd*Aen[2]), __expf(sumd*Aen[3]));
    *(float4*)(cA + base + 4) = make_float4(__expf(sumd*Aen[4]), __expf(sumd*Aen[5]),
                                            __expf(sumd*Aen[6]), __expf(sumd*Aen[7]));
    *(float4*)(cH + base)     = make_float4(h[0], h[1], h[2], h[3]);
    *(float4*)(cH + base + 4) = make_float4(h[4], h[5], h[6], h[7]);
  }
  grid.sync();

  // --- scan phase 2: 8192 rows, serial over NC chunks, 16-deep prefetch ---
  {
    const int ft = gid*256 + tid;
    if (ft < BB*ED*NN) {
      const size_t rbase = (size_t)(ft >> 12)*ED*NN + (ft & 4095);
      float h = 0.f;
      for (int g = 0; g < NC/16; g++) {
        float av[16], hv[16];
        #pragma unroll
        for (int i = 0; i < 16; i++) {
          const size_t idx = (size_t)(g*16 + i)*(BB*ED*NN) + rbase;
          av[i] = cA[idx]; hv[i] = cH[idx];
        }
        #pragma unroll
        for (int i = 0; i < 16; i++) {
          const size_t idx = (size_t)(g*16 + i)*(BB*ED*NN) + rbase;
          cA[idx] = h;                 // prefix (carry-in for chunk)
          h = av[i]*h + hv[i];
        }
      }
    }
  }
  grid.sync();

  // --- scan phase 3: replay with prefix, reduce n, gate, write bf16 y ---
  {
    const float Dpe = Dpv[e];
    const float4 h0v = *(const float4*)(cA + base);
    const float4 h1v = *(const float4*)(cA + base + 4);
    float h[8] = {h0v.x,h0v.y,h0v.z,h0v.w,h1v.x,h1v.y,h1v.z,h1v.w};
    for (int i = 0; i < LC; i++) {
      const float dv = sdel[i][e_loc];
      const float uv = su[i][e_loc];
      const float du = dv * uv;
      const float4 B0 = *(const float4*)&sdbc[i][RR + n0];
      const float4 B1 = *(const float4*)&sdbc[i][RR + n0 + 4];
      const float4 C0 = *(const float4*)&sdbc[i][RR + NN + n0];
      const float4 C1 = *(const float4*)&sdbc[i][RR + NN + n0 + 4];
      const float Bv[8] = {B0.x,B0.y,B0.z,B0.w,B1.x,B1.y,B1.z,B1.w};
      const float Cv[8] = {C0.x,C0.y,C0.z,C0.w,C1.x,C1.y,C1.z,C1.w};
      float part = 0.f;
      #pragma unroll
      for (int j = 0; j < 8; j++) {
        h[j] = __expf(dv * Aen[j])*h[j] + Bv[j]*du;
        part += h[j]*Cv[j];
      }
      part += __shfl_xor(part, 1);     // combine the two n-halves
      if (half == 0) {
        const float zv = xz[(size_t)(t0+i)*(2*ED) + ED + e];
        const float g = zv / (1.f + __expf(-zv));   // silu(z)
        ybf[(size_t)(t0+i)*ED + e] = f2bf((part + uv*Dpe) * g);
      }
    }
  }
}

// ---------------------------------------------------------------------------
extern "C" void kernel_launch(void* const* d_in, const int* in_sizes, int n_in,
                              void* d_out, int out_size, void* d_ws, size_t ws_size,
                              hipStream_t stream) {
  const float* x      = (const float*)d_in[0];
  const float* n1g    = (const float*)d_in[1];
  const float* n1b    = (const float*)d_in[2];
  const float* ing    = (const float*)d_in[3];
  const float* inb    = (const float*)d_in[4];
  const float* in_w   = (const float*)d_in[5];
  const float* conv_w = (const float*)d_in[6];
  const float* conv_b = (const float*)d_in[7];
  const float* xproj_w= (const float*)d_in[8];
  const float* dt_w   = (const float*)d_in[9];
  const float* dt_b   = (const float*)d_in[10];
  const float* A_log  = (const float*)d_in[11];
  const float* Dpv    = (const float*)d_in[12];
  const float* out_w  = (const float*)d_in[13];
  const float* fc1_w  = (const float*)d_in[14];
  const float* fc1_b  = (const float*)d_in[15];
  const float* fc2_w  = (const float*)d_in[16];
  const float* fc2_b  = (const float*)d_in[17];
  float* out = (float*)d_out;

  // Workspace layout. ~30 MB total.
  float* ws    = (float*)d_ws;
  float* xz    = ws;                          // [NT,512] fp32
  float* cAP   = xz    + (size_t)NT*2*ED;     // [NC,B,ED,N]
  float* cH    = cAP   + (size_t)NC*BB*ED*NN;
  float* xnew  = cH    + (size_t)NC*BB*ED*NN; // [NT,128]
  unsigned short* xnbf  = (unsigned short*)(xnew + (size_t)NT*DD);
  unsigned short* ybf   = xnbf  + (size_t)NT*DD;   // [NT,256] bf16
  unsigned short* hlnbf = ybf   + (size_t)NT*ED;   // [NT,128] bf16
  unsigned short* hmlbf = hlnbf + (size_t)NT*DD;   // [NT,256] bf16
  unsigned short* wbin  = hmlbf + (size_t)NT*HH;   // 512x128 bf16
  unsigned short* wbout = wbin  + (size_t)2*ED*DD; // 128x256
  unsigned short* wbf1  = wbout + (size_t)DD*ED;   // 256x128
  unsigned short* wbf2  = wbf1  + (size_t)HH*DD;   // 128x256
  unsigned short* wbxp  = wbf2  + (size_t)DD*HH;   // 40x256

  // 0) weights -> bf16 (once per launch)
  cvt5_k<<<170, 256, 0, stream>>>(in_w, out_w, fc1_w, fc2_w, xproj_w,
                                  wbin, wbout, wbf1, wbf2, wbxp);
  // 1) xnbf = bf16(inner_ln(norm1(x)))
  ln2_k<true><<<NT/4, 256, 0, stream>>>(x, n1g, n1b, ing, inb, xnbf);
  // 2) xz = xn @ in_w^T   [NT,512]
  gemm_bf_k<DD,0,float><<<dim3(512/64, NT/64), 256, 0, stream>>>(xnbf, wbin, nullptr, nullptr, xz, 2*ED);
  // 3) fused SSM core (cooperative, 512 blocks = 2/CU)
  {
    void* cargs[] = { (void*)&xz, (void*)&conv_w, (void*)&conv_b, (void*)&wbxp,
                      (void*)&dt_w, (void*)&dt_b, (void*)&A_log, (void*)&Dpv,
                      (void*)&cAP, (void*)&cH, (void*)&ybf };
    hipLaunchCooperativeKernel((const void*)mamba_core_k, dim3(2*NC*BB), dim3(256),
                               cargs, 0, stream);
  }
  // 4) xnew = y @ out_w^T + x
  gemm_bf_k<ED,1,float><<<dim3(DD/64, NT/64), 256, 0, stream>>>(ybf, wbout, nullptr, x, xnew, DD);
  // 5) hlnbf = bf16(norm1(xnew))
  ln2_k<false><<<NT/4, 256, 0, stream>>>(xnew, n1g, n1b, nullptr, nullptr, hlnbf);
  // 6) hmlbf = bf16(gelu(hln @ fc1_w^T + fc1_b))
  gemm_bf_k<DD,2,unsigned short><<<dim3(HH/64, NT/64), 256, 0, stream>>>(hlnbf, wbf1, fc1_b, nullptr, hmlbf, HH);
  // 7) out = hmlp @ fc2_w^T + fc2_b + xnew
  gemm_bf_k<HH,3,float><<<dim3(DD/64, NT/64), 256, 0, stream>>>(hmlbf, wbf2, fc2_b, xnew, out, DD);
}

// Round 7
// 198.350 us; speedup vs baseline: 1.5883x; 1.5883x over previous
//
#include <hip/hip_runtime.h>
#include <hip/hip_bf16.h>
#include <math.h>

// Problem constants (match reference)
#define BB 2
#define LL 4096
#define DD 128
#define ED 256
#define NN 16
#define KK 4
#define RR 8
#define HH 256
#define NT (BB*LL)          // 8192 tokens
#define NC 128              // chunks for scan
#define LC 32               // chunk length (NC*LC == LL)

typedef __attribute__((ext_vector_type(8))) short short8;
typedef __attribute__((ext_vector_type(8))) unsigned short ushort8v;
typedef __attribute__((ext_vector_type(4))) float floatx4;

__device__ __forceinline__ unsigned short f2bf(float f) {
  unsigned int b = __builtin_bit_cast(unsigned int, f);
  b += 0x7FFFu + ((b >> 16) & 1u);           // round-to-nearest-even
  return (unsigned short)(b >> 16);
}

// ---------------------------------------------------------------------------
// One-shot fp32->bf16 conversion of the 5 weight matrices used by MFMA paths.
// float4 units: in_w 16384 | out_w 8192 | fc1 8192 | fc2 8192 | xproj 2560
// ---------------------------------------------------------------------------
__global__ __launch_bounds__(256) void cvt5_k(const float* __restrict__ a,
    const float* __restrict__ b, const float* __restrict__ c,
    const float* __restrict__ d, const float* __restrict__ e5,
    unsigned short* __restrict__ oa, unsigned short* __restrict__ ob,
    unsigned short* __restrict__ oc, unsigned short* __restrict__ od,
    unsigned short* __restrict__ oe) {
  const int i = blockIdx.x*256 + threadIdx.x;   // < 43520 float4s
  const float* src; unsigned short* dst; int off;
  if (i < 16384)      { src = a;  dst = oa; off = i; }
  else if (i < 24576) { src = b;  dst = ob; off = i - 16384; }
  else if (i < 32768) { src = c;  dst = oc; off = i - 24576; }
  else if (i < 40960) { src = d;  dst = od; off = i - 32768; }
  else                { src = e5; dst = oe; off = i - 40960; }
  const float4 v = ((const float4*)src)[off];
  unsigned int lo = f2bf(v.x) | ((unsigned int)f2bf(v.y) << 16);
  unsigned int hi = f2bf(v.z) | ((unsigned int)f2bf(v.w) << 16);
  ((uint2*)dst)[off] = make_uint2(lo, hi);
}

// ---------------------------------------------------------------------------
// in_proj GEMM with fused double-LayerNorm on A. xz[M,512] = LN2(LN1(x)) @ W^T
// K = 128 = LN width. A-staging threads (4 per row, 32 floats each) compute
// row stats via 2 shuffles, apply both LNs, convert bf16 -> LDS.
// ---------------------------------------------------------------------------
__global__ __launch_bounds__(256) void gemm_inln_k(const float* __restrict__ x,
    const float* __restrict__ g1, const float* __restrict__ b1,
    const float* __restrict__ g2, const float* __restrict__ b2,
    const unsigned short* __restrict__ W, float* __restrict__ C) {
  __shared__ unsigned short As[64][136];
  __shared__ unsigned short Ws[64][136];
  const int row0 = blockIdx.y * 64;
  const int col0 = blockIdx.x * 64;
  const int tid  = threadIdx.x;
  const int wave = tid >> 6, lane = tid & 63;
  const int quad = lane >> 4, l16 = lane & 15;
  const int wm = (wave & 1) * 32, wn = (wave >> 1) * 32;
  const int lr = tid >> 2;            // staging row 0..63
  const int lk = (tid & 3) * 32;      // staging col (32 floats)

  // --- A staging with double LN ---
  {
    const float* Ap = x + (size_t)(row0 + lr)*DD + lk;
    float4 av[8];
    float s = 0.f, sq = 0.f;
    #pragma unroll
    for (int g = 0; g < 8; g++) {
      av[g] = *(const float4*)(Ap + g*4);
      s  += av[g].x + av[g].y + av[g].z + av[g].w;
      sq += av[g].x*av[g].x + av[g].y*av[g].y + av[g].z*av[g].z + av[g].w*av[g].w;
    }
    s += __shfl_xor(s, 1);  s += __shfl_xor(s, 2);
    sq += __shfl_xor(sq, 1); sq += __shfl_xor(sq, 2);
    const float m1 = s * (1.f/128.f);
    const float rs1 = rsqrtf(sq*(1.f/128.f) - m1*m1 + 1e-5f);
    float s2 = 0.f, sq2 = 0.f;
    #pragma unroll
    for (int g = 0; g < 8; g++) {
      const float4 gg = *(const float4*)(g1 + lk + g*4);
      const float4 bb = *(const float4*)(b1 + lk + g*4);
      av[g].x = (av[g].x - m1)*rs1*gg.x + bb.x;
      av[g].y = (av[g].y - m1)*rs1*gg.y + bb.y;
      av[g].z = (av[g].z - m1)*rs1*gg.z + bb.z;
      av[g].w = (av[g].w - m1)*rs1*gg.w + bb.w;
      s2  += av[g].x + av[g].y + av[g].z + av[g].w;
      sq2 += av[g].x*av[g].x + av[g].y*av[g].y + av[g].z*av[g].z + av[g].w*av[g].w;
    }
    s2 += __shfl_xor(s2, 1);  s2 += __shfl_xor(s2, 2);
    sq2 += __shfl_xor(sq2, 1); sq2 += __shfl_xor(sq2, 2);
    const float m2 = s2 * (1.f/128.f);
    const float rs2 = rsqrtf(sq2*(1.f/128.f) - m2*m2 + 1e-5f);
    #pragma unroll
    for (int g = 0; g < 4; g++) {
      const float4 ga = *(const float4*)(g2 + lk + g*8);
      const float4 gb = *(const float4*)(g2 + lk + g*8 + 4);
      const float4 ba = *(const float4*)(b2 + lk + g*8);
      const float4 bbv= *(const float4*)(b2 + lk + g*8 + 4);
      ushort8v pa;
      pa[0] = f2bf((av[2*g].x   - m2)*rs2*ga.x + ba.x);
      pa[1] = f2bf((av[2*g].y   - m2)*rs2*ga.y + ba.y);
      pa[2] = f2bf((av[2*g].z   - m2)*rs2*ga.z + ba.z);
      pa[3] = f2bf((av[2*g].w   - m2)*rs2*ga.w + ba.w);
      pa[4] = f2bf((av[2*g+1].x - m2)*rs2*gb.x + bbv.x);
      pa[5] = f2bf((av[2*g+1].y - m2)*rs2*gb.y + bbv.y);
      pa[6] = f2bf((av[2*g+1].z - m2)*rs2*gb.z + bbv.z);
      pa[7] = f2bf((av[2*g+1].w - m2)*rs2*gb.w + bbv.w);
      *(ushort8v*)&As[lr][lk + g*8] = pa;
    }
  }
  // --- W staging (bf16 copy) ---
  {
    const unsigned short* Wp = W + (size_t)(col0 + lr)*DD + lk;
    #pragma unroll
    for (int g = 0; g < 4; g++)
      *(ushort8v*)&Ws[lr][lk + g*8] = *(const ushort8v*)(Wp + g*8);
  }
  __syncthreads();

  floatx4 acc[2][2] = {};
  #pragma unroll
  for (int ks = 0; ks < 4; ks++) {
    const int ko = ks*32 + quad*8;
    short8 a0 = *(const short8*)&As[wm +      l16][ko];
    short8 a1 = *(const short8*)&As[wm + 16 + l16][ko];
    short8 b0 = *(const short8*)&Ws[wn +      l16][ko];
    short8 b1 = *(const short8*)&Ws[wn + 16 + l16][ko];
    acc[0][0] = __builtin_amdgcn_mfma_f32_16x16x32_bf16(a0, b0, acc[0][0], 0, 0, 0);
    acc[0][1] = __builtin_amdgcn_mfma_f32_16x16x32_bf16(a0, b1, acc[0][1], 0, 0, 0);
    acc[1][0] = __builtin_amdgcn_mfma_f32_16x16x32_bf16(a1, b0, acc[1][0], 0, 0, 0);
    acc[1][1] = __builtin_amdgcn_mfma_f32_16x16x32_bf16(a1, b1, acc[1][1], 0, 0, 0);
  }
  #pragma unroll
  for (int i = 0; i < 2; i++)
    #pragma unroll
    for (int j = 0; j < 2; j++) {
      const int n = col0 + wn + j*16 + l16;
      #pragma unroll
      for (int r = 0; r < 4; r++) {
        const int m = row0 + wm + i*16 + quad*4 + r;
        C[(size_t)m*(2*ED) + n] = acc[i][j][r];
      }
    }
}

// ---------------------------------------------------------------------------
// bf16 MFMA GEMM (fc1/fc2): C[M,Nn] = A[M,KD] @ W[Nn,KD]^T.
// EPI: 2 = gelu(+bias) bf16-out; 3 = +bias +res fp32-out
// ---------------------------------------------------------------------------
template<int KD, int EPI, typename OT>
__global__ __launch_bounds__(256) void gemm_bf_k(
    const unsigned short* __restrict__ A, const unsigned short* __restrict__ W,
    const float* __restrict__ bias, const float* __restrict__ res,
    OT* __restrict__ C, int Nn) {
  static_assert(KD % 128 == 0, "KD multiple of 128");
  __shared__ unsigned short As[64][136];
  __shared__ unsigned short Ws[64][136];
  const int row0 = blockIdx.y * 64;
  const int col0 = blockIdx.x * 64;
  const int tid  = threadIdx.x;
  const int wave = tid >> 6, lane = tid & 63;
  const int quad = lane >> 4, l16 = lane & 15;
  const int wm = (wave & 1) * 32, wn = (wave >> 1) * 32;
  const int lr = tid >> 2, lc = (tid & 3) * 32;

  floatx4 acc[2][2] = {};
  for (int ks0 = 0; ks0 < KD; ks0 += 128) {
    const unsigned short* Ap = A + (size_t)(row0 + lr)*KD + ks0 + lc;
    const unsigned short* Wp = W + (size_t)(col0 + lr)*KD + ks0 + lc;
    ushort8v av[4], wv[4];
    #pragma unroll
    for (int g = 0; g < 4; g++) {
      av[g] = *(const ushort8v*)(Ap + g*8);
      wv[g] = *(const ushort8v*)(Wp + g*8);
    }
    __syncthreads();
    #pragma unroll
    for (int g = 0; g < 4; g++) {
      *(ushort8v*)&As[lr][lc + g*8] = av[g];
      *(ushort8v*)&Ws[lr][lc + g*8] = wv[g];
    }
    __syncthreads();
    #pragma unroll
    for (int ks = 0; ks < 4; ks++) {
      const int ko = ks*32 + quad*8;
      short8 a0 = *(const short8*)&As[wm +      l16][ko];
      short8 a1 = *(const short8*)&As[wm + 16 + l16][ko];
      short8 b0 = *(const short8*)&Ws[wn +      l16][ko];
      short8 b1 = *(const short8*)&Ws[wn + 16 + l16][ko];
      acc[0][0] = __builtin_amdgcn_mfma_f32_16x16x32_bf16(a0, b0, acc[0][0], 0, 0, 0);
      acc[0][1] = __builtin_amdgcn_mfma_f32_16x16x32_bf16(a0, b1, acc[0][1], 0, 0, 0);
      acc[1][0] = __builtin_amdgcn_mfma_f32_16x16x32_bf16(a1, b0, acc[1][0], 0, 0, 0);
      acc[1][1] = __builtin_amdgcn_mfma_f32_16x16x32_bf16(a1, b1, acc[1][1], 0, 0, 0);
    }
  }
  #pragma unroll
  for (int i = 0; i < 2; i++)
    #pragma unroll
    for (int j = 0; j < 2; j++) {
      const int n = col0 + wn + j*16 + l16;
      const float bn = bias[n];
      #pragma unroll
      for (int r = 0; r < 4; r++) {
        const int m = row0 + wm + i*16 + quad*4 + r;
        float v = acc[i][j][r] + bn;
        if constexpr (EPI == 2) v = 0.5f*v*(1.f + erff(v*0.70710678118f));
        const size_t o = (size_t)m*Nn + n;
        if constexpr (EPI == 3) v += res[o];
        if constexpr (sizeof(OT) == 2) C[o] = (OT)f2bf(v);
        else                           C[o] = v;
      }
    }
}

// ---------------------------------------------------------------------------
// Fused scan phase 1: conv+silu -> xproj(MFMA) -> delta -> per-chunk scan
// summaries. Grid (eb, c, b); conv/xproj duplicated across e-half blocks.
// Writes uc/delta (own 128 channels), dbc (eb==0), cA/cH.
// ---------------------------------------------------------------------------
__global__ __launch_bounds__(256) void scan1f_k(
    const float* __restrict__ xz, const float* __restrict__ cw,
    const float* __restrict__ cb, const unsigned short* __restrict__ xpwb,
    const float* __restrict__ dtw, const float* __restrict__ dtb,
    const float* __restrict__ A_log, float* __restrict__ uc,
    float* __restrict__ dbc, float* __restrict__ delta,
    float* __restrict__ cA, float* __restrict__ cH) {
  __shared__ __align__(16) unsigned short Bs[64][264];
  __shared__ __align__(16) unsigned short As[32][264];
  __shared__ float su[32][128];
  __shared__ float sdbc[32][40];
  float (*sdel)[128] = reinterpret_cast<float(*)[128]>(&As[0][0]); // aliases As

  const int eb = blockIdx.x, c = blockIdx.y, b = blockIdx.z;
  const int tid = threadIdx.x;
  const int t0 = b*LL + c*LC;

  // stage xproj weights (rows >= 40 zeroed)
  #pragma unroll
  for (int p = 0; p < 8; p++) {
    const int idx = p*256 + tid;
    const int row = idx >> 5;
    const int col = (idx & 31) * 8;
    ushort8v v = {};
    if (row < 40) v = *(const ushort8v*)(xpwb + row*ED + col);
    *(ushort8v*)&Bs[row][col] = v;
  }

  // conv: rolling window, all 256 channels
  {
    const int ch = tid;
    const float4 w = *(const float4*)(cw + ch*4);
    const float cbe = cb[ch];
    float h0 = 0.f, h1 = 0.f, h2 = 0.f;
    if (c != 0) {
      h0 = xz[(size_t)(t0-3)*(2*ED) + ch];
      h1 = xz[(size_t)(t0-2)*(2*ED) + ch];
      h2 = xz[(size_t)(t0-1)*(2*ED) + ch];
    }
    const bool own = (ch >> 7) == eb;
    #pragma unroll 8
    for (int i = 0; i < LC; i++) {
      const float cur = xz[(size_t)(t0+i)*(2*ED) + ch];
      const float a = cbe + h0*w.x + h1*w.y + h2*w.z + cur*w.w;
      const float s = a / (1.f + __expf(-a));
      As[i][ch] = f2bf(s);
      if (own) {
        su[i][ch & 127] = s;
        uc[(size_t)(t0+i)*ED + ch] = s;
      }
      h0 = h1; h1 = h2; h2 = cur;
    }
  }
  __syncthreads();

  // xproj MFMA: M=32, N=64(pad), K=256
  const int wave = tid >> 6, lane = tid & 63;
  const int quad = lane >> 4, l16 = lane & 15;
  {
    const int mi = (wave & 1) * 16;
    const int j0 = (wave >> 1) * 2;
    floatx4 acc[2] = {};
    #pragma unroll
    for (int ks = 0; ks < 8; ks++) {
      const int ko = ks*32 + quad*8;
      short8 a  = *(const short8*)&As[mi + l16][ko];
      short8 b0 = *(const short8*)&Bs[j0*16 +      l16][ko];
      short8 b1 = *(const short8*)&Bs[j0*16 + 16 + l16][ko];
      acc[0] = __builtin_amdgcn_mfma_f32_16x16x32_bf16(a, b0, acc[0], 0, 0, 0);
      acc[1] = __builtin_amdgcn_mfma_f32_16x16x32_bf16(a, b1, acc[1], 0, 0, 0);
    }
    __syncthreads();   // As reads done before sdel aliases As
    #pragma unroll
    for (int f = 0; f < 2; f++) {
      const int n = (j0 + f)*16 + l16;
      #pragma unroll
      for (int r = 0; r < 4; r++) {
        const int m = mi + quad*4 + r;
        if (n < 40) {
          sdbc[m][n] = acc[f][r];
          if (eb == 0) dbc[(size_t)(t0 + m)*40 + n] = acc[f][r];
        }
      }
    }
  }
  __syncthreads();

  // delta: softplus(dt @ dt_w^T + dt_b) for own 128 channels
  const int e_loc = tid >> 1;
  const int half  = tid & 1;
  const int e     = eb*128 + e_loc;
  {
    const float4 w0 = *(const float4*)(dtw + e*RR);
    const float4 w1 = *(const float4*)(dtw + e*RR + 4);
    const float db = dtb[e];
    #pragma unroll 4
    for (int i = 0; i < 16; i++) {
      const int t = half*16 + i;
      const float a = db
          + sdbc[t][0]*w0.x + sdbc[t][1]*w0.y + sdbc[t][2]*w0.z + sdbc[t][3]*w0.w
          + sdbc[t][4]*w1.x + sdbc[t][5]*w1.y + sdbc[t][6]*w1.z + sdbc[t][7]*w1.w;
      const float d = (a > 20.f) ? a : log1pf(__expf(a));
      sdel[t][e_loc] = d;
      delta[(size_t)(t0+t)*ED + e] = d;
    }
  }
  __syncthreads();

  // per-chunk scan summaries; thread owns (e, n-half)
  const int n0 = half * 8;
  const float4 a0 = *(const float4*)(A_log + e*NN + n0);
  const float4 a1 = *(const float4*)(A_log + e*NN + n0 + 4);
  float Aen[8] = {-__expf(a0.x), -__expf(a0.y), -__expf(a0.z), -__expf(a0.w),
                  -__expf(a1.x), -__expf(a1.y), -__expf(a1.z), -__expf(a1.w)};
  float h[8] = {};
  float sumd = 0.f;
  for (int i = 0; i < LC; i++) {
    const float dv = sdel[i][e_loc];
    const float du = dv * su[i][e_loc];
    const float4 B0 = *(const float4*)&sdbc[i][RR + n0];
    const float4 B1 = *(const float4*)&sdbc[i][RR + n0 + 4];
    const float Bv[8] = {B0.x,B0.y,B0.z,B0.w,B1.x,B1.y,B1.z,B1.w};
    sumd += dv;
    #pragma unroll
    for (int j = 0; j < 8; j++)
      h[j] = __expf(dv * Aen[j])*h[j] + Bv[j]*du;
  }
  const size_t base = (((size_t)c*BB + b)*ED + e)*NN + n0;
  *(float4*)(cA + base)     = make_float4(__expf(sumd*Aen[0]), __expf(sumd*Aen[1]),
                                          __expf(sumd*Aen[2]), __expf(sumd*Aen[3]));
  *(float4*)(cA + base + 4) = make_float4(__expf(sumd*Aen[4]), __expf(sumd*Aen[5]),
                                          __expf(sumd*Aen[6]), __expf(sumd*Aen[7]));
  *(float4*)(cH + base)     = make_float4(h[0], h[1], h[2], h[3]);
  *(float4*)(cH + base + 4) = make_float4(h[4], h[5], h[6], h[7]);
}

// ---------------------------------------------------------------------------
// Scan phase 2: scan over NC chunk summaries, in-place prefix into cA.
// ---------------------------------------------------------------------------
__global__ __launch_bounds__(256) void scan2_k(float* __restrict__ cA,
    const float* __restrict__ cH) {
  const int gt = blockIdx.x*256 + threadIdx.x;   // [0, BB*ED*NN)
  const int b = gt >> 12;
  const size_t base = (size_t)b*ED*NN + (gt & 4095);
  float h = 0.f;
  for (int c = 0; c < NC; c++) {
    const size_t idx = (size_t)c*(BB*ED*NN) + base;
    const float a = cA[idx], hh = cH[idx];
    cA[idx] = h;
    h = a*h + hh;
  }
}

// ---------------------------------------------------------------------------
// Scan phase 3: replay with prefix, n-reduction in regs (+1 shuffle),
// fused gating: y = (scan_y + u*Dp) * silu(z). bf16 out.
// ---------------------------------------------------------------------------
__global__ __launch_bounds__(256) void scan3_k(const float* __restrict__ delta,
    const float* __restrict__ uc, const float* __restrict__ dbc,
    const float* __restrict__ xz, const float* __restrict__ A_log,
    const float* __restrict__ Dpv, const float* __restrict__ cP,
    unsigned short* __restrict__ ybf) {
  const int c = blockIdx.y, b = blockIdx.z;
  const int e    = blockIdx.x*128 + (threadIdx.x >> 1);
  const int half = threadIdx.x & 1;
  const int n0   = half * 8;
  const float4 a0 = *(const float4*)(A_log + e*NN + n0);
  const float4 a1 = *(const float4*)(A_log + e*NN + n0 + 4);
  float Aen[8] = {-__expf(a0.x), -__expf(a0.y), -__expf(a0.z), -__expf(a0.w),
                  -__expf(a1.x), -__expf(a1.y), -__expf(a1.z), -__expf(a1.w)};
  const float Dpe = Dpv[e];
  const size_t base = (((size_t)c*BB + b)*ED + e)*NN + n0;
  const float4 h0 = *(const float4*)(cP + base);
  const float4 h1 = *(const float4*)(cP + base + 4);
  float h[8] = {h0.x,h0.y,h0.z,h0.w,h1.x,h1.y,h1.z,h1.w};
  const size_t tok0 = (size_t)b*LL + (size_t)c*LC;
  for (int i = 0; i < LC; i++) {
    const size_t t = tok0 + i;
    const float dv = delta[t*ED + e];
    const float uv = uc[t*ED + e];
    const float du = dv * uv;
    const float4 B0 = *(const float4*)(dbc + t*40 + RR + n0);
    const float4 B1 = *(const float4*)(dbc + t*40 + RR + n0 + 4);
    const float4 C0 = *(const float4*)(dbc + t*40 + RR + NN + n0);
    const float4 C1 = *(const float4*)(dbc + t*40 + RR + NN + n0 + 4);
    const float Bv[8] = {B0.x,B0.y,B0.z,B0.w,B1.x,B1.y,B1.z,B1.w};
    const float Cv[8] = {C0.x,C0.y,C0.z,C0.w,C1.x,C1.y,C1.z,C1.w};
    float part = 0.f;
    #pragma unroll
    for (int j = 0; j < 8; j++) {
      h[j] = __expf(dv * Aen[j])*h[j] + Bv[j]*du;
      part += h[j]*Cv[j];
    }
    part += __shfl_xor(part, 1);
    if (half == 0) {
      const float zv = xz[t*(2*ED) + ED + e];
      const float g = zv / (1.f + __expf(-zv));
      ybf[t*ED + e] = f2bf((part + uv*Dpe) * g);
    }
  }
}

// ---------------------------------------------------------------------------
// out_proj GEMM with fused residual + norm1 epilogue. Tile 32x128 (full row),
// KD=256. Writes xnew fp32 (final residual input) and hlnbf bf16 (fc1 input).
// ---------------------------------------------------------------------------
__global__ __launch_bounds__(256) void gemm_outln_k(
    const unsigned short* __restrict__ A, const unsigned short* __restrict__ W,
    const float* __restrict__ xres, const float* __restrict__ g1,
    const float* __restrict__ b1, float* __restrict__ xnew,
    unsigned short* __restrict__ hlnbf) {
  __shared__ unsigned short As[32][136];
  __shared__ unsigned short Ws[128][136];
  __shared__ float xs[32][132];
  const int row0 = blockIdx.x * 32;
  const int tid  = threadIdx.x;
  const int wave = tid >> 6, lane = tid & 63;
  const int quad = lane >> 4, l16 = lane & 15;
  const int wm = (wave & 1) * 16;      // 1 m-frag
  const int wn = (wave >> 1) * 64;     // 4 n-frags

  floatx4 acc[4] = {};
  for (int ks0 = 0; ks0 < ED; ks0 += 128) {
    // A: 32 rows x 128 k (8 threads/row, 16 shorts each)
    const int lr = tid >> 3, lk = (tid & 7) * 16;
    ushort8v a0 = *(const ushort8v*)(A + (size_t)(row0 + lr)*ED + ks0 + lk);
    ushort8v a1 = *(const ushort8v*)(A + (size_t)(row0 + lr)*ED + ks0 + lk + 8);
    // W: 128 rows x 128 k (2 threads/row, 64 shorts each)
    const int wr = tid >> 1, wk = (tid & 1) * 64;
    ushort8v wv[8];
    #pragma unroll
    for (int g = 0; g < 8; g++)
      wv[g] = *(const ushort8v*)(W + (size_t)wr*ED + ks0 + wk + g*8);
    __syncthreads();
    *(ushort8v*)&As[lr][lk]     = a0;
    *(ushort8v*)&As[lr][lk + 8] = a1;
    #pragma unroll
    for (int g = 0; g < 8; g++) *(ushort8v*)&Ws[wr][wk + g*8] = wv[g];
    __syncthreads();
    #pragma unroll
    for (int ks = 0; ks < 4; ks++) {
      const int ko = ks*32 + quad*8;
      short8 a = *(const short8*)&As[wm + l16][ko];
      #pragma unroll
      for (int f = 0; f < 4; f++) {
        short8 b = *(const short8*)&Ws[wn + f*16 + l16][ko];
        acc[f] = __builtin_amdgcn_mfma_f32_16x16x32_bf16(a, b, acc[f], 0, 0, 0);
      }
    }
  }
  // residual into LDS row buffer
  #pragma unroll
  for (int f = 0; f < 4; f++) {
    const int n = wn + f*16 + l16;
    #pragma unroll
    for (int r = 0; r < 4; r++) {
      const int m = wm + quad*4 + r;
      xs[m][n] = acc[f][r] + xres[(size_t)(row0 + m)*DD + n];
    }
  }
  __syncthreads();
  // norm1 over each full row; 8 threads/row, 16 elems each
  {
    const int lr = tid >> 3, le = (tid & 7) * 16;
    float vv[16];
    float s = 0.f, sq = 0.f;
    #pragma unroll
    for (int i = 0; i < 16; i++) {
      vv[i] = xs[lr][le + i];
      s += vv[i]; sq += vv[i]*vv[i];
    }
    s += __shfl_xor(s, 1);  s += __shfl_xor(s, 2);  s += __shfl_xor(s, 4);
    sq += __shfl_xor(sq, 1); sq += __shfl_xor(sq, 2); sq += __shfl_xor(sq, 4);
    const float mean = s * (1.f/128.f);
    const float rs = rsqrtf(sq*(1.f/128.f) - mean*mean + 1e-5f);
    const size_t ro = (size_t)(row0 + lr)*DD + le;
    #pragma unroll
    for (int g = 0; g < 4; g++)
      *(float4*)(xnew + ro + g*4) = make_float4(vv[4*g], vv[4*g+1], vv[4*g+2], vv[4*g+3]);
    #pragma unroll
    for (int g = 0; g < 2; g++) {
      ushort8v p;
      #pragma unroll
      for (int i = 0; i < 8; i++) {
        const int idx = g*8 + i;
        p[i] = f2bf((vv[idx] - mean)*rs*g1[le + idx] + b1[le + idx]);
      }
      *(ushort8v*)(hlnbf + ro + g*8) = p;
    }
  }
}

// ---------------------------------------------------------------------------
extern "C" void kernel_launch(void* const* d_in, const int* in_sizes, int n_in,
                              void* d_out, int out_size, void* d_ws, size_t ws_size,
                              hipStream_t stream) {
  const float* x      = (const float*)d_in[0];
  const float* n1g    = (const float*)d_in[1];
  const float* n1b    = (const float*)d_in[2];
  const float* ing    = (const float*)d_in[3];
  const float* inb    = (const float*)d_in[4];
  const float* in_w   = (const float*)d_in[5];
  const float* conv_w = (const float*)d_in[6];
  const float* conv_b = (const float*)d_in[7];
  const float* xproj_w= (const float*)d_in[8];
  const float* dt_w   = (const float*)d_in[9];
  const float* dt_b   = (const float*)d_in[10];
  const float* A_log  = (const float*)d_in[11];
  const float* Dpv    = (const float*)d_in[12];
  const float* out_w  = (const float*)d_in[13];
  const float* fc1_w  = (const float*)d_in[14];
  const float* fc1_b  = (const float*)d_in[15];
  const float* fc2_w  = (const float*)d_in[16];
  const float* fc2_b  = (const float*)d_in[17];
  float* out = (float*)d_out;

  // Workspace layout (~56 MB)
  float* ws    = (float*)d_ws;
  float* xz    = ws;                          // [NT,512]
  float* uc    = xz    + (size_t)NT*2*ED;     // [NT,256]
  float* dbc   = uc    + (size_t)NT*ED;       // [NT,40]
  float* delta = dbc   + (size_t)NT*40;       // [NT,256]
  float* cAP   = delta + (size_t)NT*ED;       // [NC,B,ED,N]
  float* cH    = cAP   + (size_t)NC*BB*ED*NN;
  float* xnew  = cH    + (size_t)NC*BB*ED*NN; // [NT,128]
  unsigned short* ybf   = (unsigned short*)(xnew + (size_t)NT*DD);
  unsigned short* hlnbf = ybf   + (size_t)NT*ED;   // [NT,128]
  unsigned short* hmlbf = hlnbf + (size_t)NT*DD;   // [NT,256]
  unsigned short* wbin  = hmlbf + (size_t)NT*HH;   // 512x128
  unsigned short* wbout = wbin  + (size_t)2*ED*DD; // 128x256
  unsigned short* wbf1  = wbout + (size_t)DD*ED;   // 256x128
  unsigned short* wbf2  = wbf1  + (size_t)HH*DD;   // 128x256
  unsigned short* wbxp  = wbf2  + (size_t)DD*HH;   // 40x256

  // 0) weights -> bf16
  cvt5_k<<<170, 256, 0, stream>>>(in_w, out_w, fc1_w, fc2_w, xproj_w,
                                  wbin, wbout, wbf1, wbf2, wbxp);
  // 1) xz = LN2(LN1(x)) @ in_w^T   (LN fused into A-staging)
  gemm_inln_k<<<dim3(512/64, NT/64), 256, 0, stream>>>(x, n1g, n1b, ing, inb, wbin, xz);
  // 2) conv+silu -> xproj(MFMA) -> delta -> chunk summaries
  scan1f_k<<<dim3(2, NC, BB), 256, 0, stream>>>(xz, conv_w, conv_b, wbxp, dt_w, dt_b,
                                                A_log, uc, dbc, delta, cAP, cH);
  // 3) inter-chunk prefix
  scan2_k<<<(BB*ED*NN)/256, 256, 0, stream>>>(cAP, cH);
  // 4) replay + gate -> ybf
  scan3_k<<<dim3(2, NC, BB), 256, 0, stream>>>(delta, uc, dbc, xz, A_log, Dpv, cAP, ybf);
  // 5) xnew = y @ out_w^T + x; hlnbf = bf16(norm1(xnew))   (fused epilogue)
  gemm_outln_k<<<NT/32, 256, 0, stream>>>(ybf, wbout, x, n1g, n1b, xnew, hlnbf);
  // 6) hmlbf = bf16(gelu(hln @ fc1_w^T + fc1_b))
  gemm_bf_k<DD,2,unsigned short><<<dim3(HH/64, NT/64), 256, 0, stream>>>(hlnbf, wbf1, fc1_b, nullptr, hmlbf, HH);
  // 7) out = hmlp @ fc2_w^T + fc2_b + xnew
  gemm_bf_k<HH,3,float><<<dim3(DD/64, NT/64), 256, 0, stream>>>(hmlbf, wbf2, fc2_b, xnew, out, DD);
}

// Round 8
// 188.739 us; speedup vs baseline: 1.6692x; 1.0509x over previous
//
#include <hip/hip_runtime.h>
#include <hip/hip_bf16.h>
#include <math.h>

// Problem constants (match reference)
#define BB 2
#define LL 4096
#define DD 128
#define ED 256
#define NN 16
#define KK 4
#define RR 8
#define HH 256
#define NT (BB*LL)          // 8192 tokens
#define NC 128              // chunks for scan
#define LC 32               // chunk length (NC*LC == LL)

typedef __attribute__((ext_vector_type(8))) short short8;
typedef __attribute__((ext_vector_type(8))) unsigned short ushort8v;
typedef __attribute__((ext_vector_type(4))) float floatx4;

__device__ __forceinline__ unsigned short f2bf(float f) {
  unsigned int b = __builtin_bit_cast(unsigned int, f);
  b += 0x7FFFu + ((b >> 16) & 1u);           // round-to-nearest-even
  return (unsigned short)(b >> 16);
}

__device__ __forceinline__ ushort8v pack8(const float4& v0, const float4& v1) {
  ushort8v p;
  p[0]=f2bf(v0.x); p[1]=f2bf(v0.y); p[2]=f2bf(v0.z); p[3]=f2bf(v0.w);
  p[4]=f2bf(v1.x); p[5]=f2bf(v1.y); p[6]=f2bf(v1.z); p[7]=f2bf(v1.w);
  return p;
}

// ---------------------------------------------------------------------------
// in_proj GEMM with fused double-LayerNorm on A and inline fp32->bf16 weight
// conversion. xz[M,512] = LN2(LN1(x)) @ in_w^T.  K = 128 = LN width.
// ---------------------------------------------------------------------------
__global__ __launch_bounds__(256) void gemm_inln_k(const float* __restrict__ x,
    const float* __restrict__ g1, const float* __restrict__ b1,
    const float* __restrict__ g2, const float* __restrict__ b2,
    const float* __restrict__ W, float* __restrict__ C) {
  __shared__ unsigned short As[64][136];
  __shared__ unsigned short Ws[64][136];
  const int row0 = blockIdx.y * 64;
  const int col0 = blockIdx.x * 64;
  const int tid  = threadIdx.x;
  const int wave = tid >> 6, lane = tid & 63;
  const int quad = lane >> 4, l16 = lane & 15;
  const int wm = (wave & 1) * 32, wn = (wave >> 1) * 32;
  const int lr = tid >> 2;            // staging row 0..63
  const int lk = (tid & 3) * 32;      // staging col (32 floats)

  // --- A staging with double LN ---
  {
    const float* Ap = x + (size_t)(row0 + lr)*DD + lk;
    float4 av[8];
    float s = 0.f, sq = 0.f;
    #pragma unroll
    for (int g = 0; g < 8; g++) {
      av[g] = *(const float4*)(Ap + g*4);
      s  += av[g].x + av[g].y + av[g].z + av[g].w;
      sq += av[g].x*av[g].x + av[g].y*av[g].y + av[g].z*av[g].z + av[g].w*av[g].w;
    }
    s += __shfl_xor(s, 1);  s += __shfl_xor(s, 2);
    sq += __shfl_xor(sq, 1); sq += __shfl_xor(sq, 2);
    const float m1 = s * (1.f/128.f);
    const float rs1 = rsqrtf(sq*(1.f/128.f) - m1*m1 + 1e-5f);
    float s2 = 0.f, sq2 = 0.f;
    #pragma unroll
    for (int g = 0; g < 8; g++) {
      const float4 gg = *(const float4*)(g1 + lk + g*4);
      const float4 bb = *(const float4*)(b1 + lk + g*4);
      av[g].x = (av[g].x - m1)*rs1*gg.x + bb.x;
      av[g].y = (av[g].y - m1)*rs1*gg.y + bb.y;
      av[g].z = (av[g].z - m1)*rs1*gg.z + bb.z;
      av[g].w = (av[g].w - m1)*rs1*gg.w + bb.w;
      s2  += av[g].x + av[g].y + av[g].z + av[g].w;
      sq2 += av[g].x*av[g].x + av[g].y*av[g].y + av[g].z*av[g].z + av[g].w*av[g].w;
    }
    s2 += __shfl_xor(s2, 1);  s2 += __shfl_xor(s2, 2);
    sq2 += __shfl_xor(sq2, 1); sq2 += __shfl_xor(sq2, 2);
    const float m2 = s2 * (1.f/128.f);
    const float rs2 = rsqrtf(sq2*(1.f/128.f) - m2*m2 + 1e-5f);
    #pragma unroll
    for (int g = 0; g < 4; g++) {
      const float4 ga = *(const float4*)(g2 + lk + g*8);
      const float4 gb = *(const float4*)(g2 + lk + g*8 + 4);
      const float4 ba = *(const float4*)(b2 + lk + g*8);
      const float4 bbv= *(const float4*)(b2 + lk + g*8 + 4);
      ushort8v pa;
      pa[0] = f2bf((av[2*g].x   - m2)*rs2*ga.x + ba.x);
      pa[1] = f2bf((av[2*g].y   - m2)*rs2*ga.y + ba.y);
      pa[2] = f2bf((av[2*g].z   - m2)*rs2*ga.z + ba.z);
      pa[3] = f2bf((av[2*g].w   - m2)*rs2*ga.w + ba.w);
      pa[4] = f2bf((av[2*g+1].x - m2)*rs2*gb.x + bbv.x);
      pa[5] = f2bf((av[2*g+1].y - m2)*rs2*gb.y + bbv.y);
      pa[6] = f2bf((av[2*g+1].z - m2)*rs2*gb.z + bbv.z);
      pa[7] = f2bf((av[2*g+1].w - m2)*rs2*gb.w + bbv.w);
      *(ushort8v*)&As[lr][lk + g*8] = pa;
    }
  }
  // --- W staging with inline conversion ---
  {
    const float* Wp = W + (size_t)(col0 + lr)*DD + lk;
    #pragma unroll
    for (int g = 0; g < 4; g++) {
      const float4 v0 = *(const float4*)(Wp + g*8);
      const float4 v1 = *(const float4*)(Wp + g*8 + 4);
      *(ushort8v*)&Ws[lr][lk + g*8] = pack8(v0, v1);
    }
  }
  __syncthreads();

  floatx4 acc[2][2] = {};
  #pragma unroll
  for (int ks = 0; ks < 4; ks++) {
    const int ko = ks*32 + quad*8;
    short8 a0 = *(const short8*)&As[wm +      l16][ko];
    short8 a1 = *(const short8*)&As[wm + 16 + l16][ko];
    short8 b0 = *(const short8*)&Ws[wn +      l16][ko];
    short8 b1 = *(const short8*)&Ws[wn + 16 + l16][ko];
    acc[0][0] = __builtin_amdgcn_mfma_f32_16x16x32_bf16(a0, b0, acc[0][0], 0, 0, 0);
    acc[0][1] = __builtin_amdgcn_mfma_f32_16x16x32_bf16(a0, b1, acc[0][1], 0, 0, 0);
    acc[1][0] = __builtin_amdgcn_mfma_f32_16x16x32_bf16(a1, b0, acc[1][0], 0, 0, 0);
    acc[1][1] = __builtin_amdgcn_mfma_f32_16x16x32_bf16(a1, b1, acc[1][1], 0, 0, 0);
  }
  #pragma unroll
  for (int i = 0; i < 2; i++)
    #pragma unroll
    for (int j = 0; j < 2; j++) {
      const int n = col0 + wn + j*16 + l16;
      #pragma unroll
      for (int r = 0; r < 4; r++) {
        const int m = row0 + wm + i*16 + quad*4 + r;
        C[(size_t)m*(2*ED) + n] = acc[i][j][r];
      }
    }
}

// ---------------------------------------------------------------------------
// Fused scan phase 1: conv+silu -> xproj(MFMA, inline W convert) -> delta ->
// per-chunk scan summaries. Grid (eb, c, b), 512 blocks, 2/CU.
// ---------------------------------------------------------------------------
__global__ __launch_bounds__(256) void scan1f_k(
    const float* __restrict__ xz, const float* __restrict__ cw,
    const float* __restrict__ cb, const float* __restrict__ xpw,
    const float* __restrict__ dtw, const float* __restrict__ dtb,
    const float* __restrict__ A_log, float* __restrict__ uc,
    float* __restrict__ dbc, float* __restrict__ delta,
    float* __restrict__ cA, float* __restrict__ cH) {
  __shared__ __align__(16) unsigned short Bs[64][264];
  __shared__ __align__(16) unsigned short As[32][264];
  __shared__ float su[32][128];
  __shared__ float sdbc[32][40];
  float (*sdel)[128] = reinterpret_cast<float(*)[128]>(&As[0][0]); // aliases As

  const int eb = blockIdx.x, c = blockIdx.y, b = blockIdx.z;
  const int tid = threadIdx.x;
  const int t0 = b*LL + c*LC;

  // stage xproj weights with inline conversion (rows >= 40 zeroed)
  #pragma unroll
  for (int p = 0; p < 8; p++) {
    const int idx = p*256 + tid;           // 2048 chunks of 8 shorts
    const int row = idx >> 5;
    const int col = (idx & 31) * 8;
    ushort8v v = {};
    if (row < 40) {
      const float4 v0 = *(const float4*)(xpw + (size_t)row*ED + col);
      const float4 v1 = *(const float4*)(xpw + (size_t)row*ED + col + 4);
      v = pack8(v0, v1);
    }
    *(ushort8v*)&Bs[row][col] = v;
  }

  // conv: rolling window, all 256 channels
  {
    const int ch = tid;
    const float4 w = *(const float4*)(cw + ch*4);
    const float cbe = cb[ch];
    float h0 = 0.f, h1 = 0.f, h2 = 0.f;
    if (c != 0) {
      h0 = xz[(size_t)(t0-3)*(2*ED) + ch];
      h1 = xz[(size_t)(t0-2)*(2*ED) + ch];
      h2 = xz[(size_t)(t0-1)*(2*ED) + ch];
    }
    const bool own = (ch >> 7) == eb;
    #pragma unroll 8
    for (int i = 0; i < LC; i++) {
      const float cur = xz[(size_t)(t0+i)*(2*ED) + ch];
      const float a = cbe + h0*w.x + h1*w.y + h2*w.z + cur*w.w;
      const float s = a / (1.f + __expf(-a));
      As[i][ch] = f2bf(s);
      if (own) {
        su[i][ch & 127] = s;
        uc[(size_t)(t0+i)*ED + ch] = s;
      }
      h0 = h1; h1 = h2; h2 = cur;
    }
  }
  __syncthreads();

  // xproj MFMA: M=32, N=64(pad), K=256
  const int wave = tid >> 6, lane = tid & 63;
  const int quad = lane >> 4, l16 = lane & 15;
  {
    const int mi = (wave & 1) * 16;
    const int j0 = (wave >> 1) * 2;
    floatx4 acc[2] = {};
    #pragma unroll
    for (int ks = 0; ks < 8; ks++) {
      const int ko = ks*32 + quad*8;
      short8 a  = *(const short8*)&As[mi + l16][ko];
      short8 b0 = *(const short8*)&Bs[j0*16 +      l16][ko];
      short8 b1 = *(const short8*)&Bs[j0*16 + 16 + l16][ko];
      acc[0] = __builtin_amdgcn_mfma_f32_16x16x32_bf16(a, b0, acc[0], 0, 0, 0);
      acc[1] = __builtin_amdgcn_mfma_f32_16x16x32_bf16(a, b1, acc[1], 0, 0, 0);
    }
    __syncthreads();   // As reads done before sdel aliases As
    #pragma unroll
    for (int f = 0; f < 2; f++) {
      const int n = (j0 + f)*16 + l16;
      #pragma unroll
      for (int r = 0; r < 4; r++) {
        const int m = mi + quad*4 + r;
        if (n < 40) {
          sdbc[m][n] = acc[f][r];
          if (eb == 0) dbc[(size_t)(t0 + m)*40 + n] = acc[f][r];
        }
      }
    }
  }
  __syncthreads();

  // delta: softplus(dt @ dt_w^T + dt_b) for own 128 channels
  const int e_loc = tid >> 1;
  const int half  = tid & 1;
  const int e     = eb*128 + e_loc;
  {
    const float4 w0 = *(const float4*)(dtw + e*RR);
    const float4 w1 = *(const float4*)(dtw + e*RR + 4);
    const float db = dtb[e];
    #pragma unroll 4
    for (int i = 0; i < 16; i++) {
      const int t = half*16 + i;
      const float a = db
          + sdbc[t][0]*w0.x + sdbc[t][1]*w0.y + sdbc[t][2]*w0.z + sdbc[t][3]*w0.w
          + sdbc[t][4]*w1.x + sdbc[t][5]*w1.y + sdbc[t][6]*w1.z + sdbc[t][7]*w1.w;
      const float d = (a > 20.f) ? a : log1pf(__expf(a));
      sdel[t][e_loc] = d;
      delta[(size_t)(t0+t)*ED + e] = d;
    }
  }
  __syncthreads();

  // per-chunk scan summaries; thread owns (e, n-half)
  const int n0 = half * 8;
  const float4 a0 = *(const float4*)(A_log + e*NN + n0);
  const float4 a1 = *(const float4*)(A_log + e*NN + n0 + 4);
  float Aen[8] = {-__expf(a0.x), -__expf(a0.y), -__expf(a0.z), -__expf(a0.w),
                  -__expf(a1.x), -__expf(a1.y), -__expf(a1.z), -__expf(a1.w)};
  float h[8] = {};
  float sumd = 0.f;
  for (int i = 0; i < LC; i++) {
    const float dv = sdel[i][e_loc];
    const float du = dv * su[i][e_loc];
    const float4 B0 = *(const float4*)&sdbc[i][RR + n0];
    const float4 B1 = *(const float4*)&sdbc[i][RR + n0 + 4];
    const float Bv[8] = {B0.x,B0.y,B0.z,B0.w,B1.x,B1.y,B1.z,B1.w};
    sumd += dv;
    #pragma unroll
    for (int j = 0; j < 8; j++)
      h[j] = __expf(dv * Aen[j])*h[j] + Bv[j]*du;
  }
  const size_t base = (((size_t)c*BB + b)*ED + e)*NN + n0;
  *(float4*)(cA + base)     = make_float4(__expf(sumd*Aen[0]), __expf(sumd*Aen[1]),
                                          __expf(sumd*Aen[2]), __expf(sumd*Aen[3]));
  *(float4*)(cA + base + 4) = make_float4(__expf(sumd*Aen[4]), __expf(sumd*Aen[5]),
                                          __expf(sumd*Aen[6]), __expf(sumd*Aen[7]));
  *(float4*)(cH + base)     = make_float4(h[0], h[1], h[2], h[3]);
  *(float4*)(cH + base + 4) = make_float4(h[4], h[5], h[6], h[7]);
}

// ---------------------------------------------------------------------------
// Scan phase 2: scan over NC chunk summaries, in-place prefix into cA.
// ---------------------------------------------------------------------------
__global__ __launch_bounds__(256) void scan2_k(float* __restrict__ cA,
    const float* __restrict__ cH) {
  const int gt = blockIdx.x*256 + threadIdx.x;   // [0, BB*ED*NN)
  const int b = gt >> 12;
  const size_t base = (size_t)b*ED*NN + (gt & 4095);
  float h = 0.f;
  for (int g = 0; g < NC/16; g++) {
    float av[16], hv[16];
    #pragma unroll
    for (int i = 0; i < 16; i++) {
      const size_t idx = (size_t)(g*16 + i)*(BB*ED*NN) + base;
      av[i] = cA[idx]; hv[i] = cH[idx];
    }
    #pragma unroll
    for (int i = 0; i < 16; i++) {
      const size_t idx = (size_t)(g*16 + i)*(BB*ED*NN) + base;
      cA[idx] = h;
      h = av[i]*h + hv[i];
    }
  }
}

// ---------------------------------------------------------------------------
// Mega-tail: scan replay + gate -> y(LDS) -> out_proj + residual -> norm1 ->
// fc1 + gelu -> fc2 + bias + residual -> out. One block per (chunk, batch):
// 256 blocks, 1/CU, 107.5 KB LDS. Weights converted bf16 per block (L2-hot).
// ---------------------------------------------------------------------------
__global__ __launch_bounds__(256, 1) void tail_k(
    const float* __restrict__ xz, const float* __restrict__ delta,
    const float* __restrict__ uc, const float* __restrict__ dbc,
    const float* __restrict__ cP, const float* __restrict__ A_log,
    const float* __restrict__ Dpv, const float* __restrict__ x,
    const float* __restrict__ g1, const float* __restrict__ b1,
    const float* __restrict__ out_w, const float* __restrict__ fc1_w,
    const float* __restrict__ fc1_b, const float* __restrict__ fc2_w,
    const float* __restrict__ fc2_b, float* __restrict__ out) {
  __shared__ __align__(16) unsigned short BigW[34816];  // 69.6 KB: Wo/W1/W2
  __shared__ __align__(16) unsigned short Au[32][264];  // y -> hln -> h (bf16)
  __shared__ float xs[32][132];                         // xnew tile fp32
  __shared__ float sbc[32][32];                         // B|C per token

  const int c = blockIdx.x, b = blockIdx.y;
  const int t0 = b*LL + c*LC;
  const int tid = threadIdx.x;
  const int wave = tid >> 6, lane = tid & 63;
  const int quad = lane >> 4, l16 = lane & 15;

  // --- stage B/C tile of dbc ---
  #pragma unroll
  for (int p = 0; p < 4; p++) {
    const int idx = p*256 + tid;
    const int row = idx >> 5, col = idx & 31;
    sbc[row][col] = dbc[(size_t)(t0 + row)*40 + RR + col];
  }

  // --- scan replay: thread = e, h[16] in regs, n-reduction in-register ---
  {
    const int e = tid;
    float Aen[16], h[16];
    #pragma unroll
    for (int g = 0; g < 4; g++) {
      const float4 a = *(const float4*)(A_log + e*NN + g*4);
      Aen[4*g]=-__expf(a.x); Aen[4*g+1]=-__expf(a.y);
      Aen[4*g+2]=-__expf(a.z); Aen[4*g+3]=-__expf(a.w);
      const float4 hp = *(const float4*)(cP + (((size_t)c*BB + b)*ED + e)*NN + g*4);
      h[4*g]=hp.x; h[4*g+1]=hp.y; h[4*g+2]=hp.z; h[4*g+3]=hp.w;
    }
    const float Dpe = Dpv[e];
    __syncthreads();     // sbc ready
    #pragma unroll 4
    for (int i = 0; i < LC; i++) {
      const float dv = delta[(size_t)(t0+i)*ED + e];
      const float uv = uc[(size_t)(t0+i)*ED + e];
      const float du = dv * uv;
      float part = 0.f;
      #pragma unroll
      for (int j = 0; j < 16; j++) {
        h[j] = __expf(dv * Aen[j])*h[j] + sbc[i][j]*du;      // B broadcast
        part += h[j]*sbc[i][16+j];                            // C broadcast
      }
      const float zv = xz[(size_t)(t0+i)*(2*ED) + ED + e];
      const float g = zv / (1.f + __expf(-zv));               // silu(z)
      Au[i][e] = f2bf((part + uv*Dpe) * g);
    }
  }
  // --- stage out_w (128x256) -> BigW bf16, stride 264 ---
  {
    const int r = tid >> 1, k0 = (tid & 1) * 128;
    const float* wp = out_w + (size_t)r*ED + k0;
    #pragma unroll
    for (int g = 0; g < 16; g++) {
      const float4 v0 = *(const float4*)(wp + g*8);
      const float4 v1 = *(const float4*)(wp + g*8 + 4);
      *(ushort8v*)&BigW[(size_t)r*264 + k0 + g*8] = pack8(v0, v1);
    }
  }
  __syncthreads();

  // --- out_proj MFMA: M=32, N=128, K=256; wave covers 32 n ---
  {
    const int wn = wave * 32;
    floatx4 acc[2][2] = {};
    #pragma unroll
    for (int ks = 0; ks < 8; ks++) {
      const int ko = ks*32 + quad*8;
      short8 a0 = *(const short8*)&Au[l16][ko];
      short8 a1 = *(const short8*)&Au[16 + l16][ko];
      short8 b0 = *(const short8*)&BigW[(size_t)(wn +      l16)*264 + ko];
      short8 b1 = *(const short8*)&BigW[(size_t)(wn + 16 + l16)*264 + ko];
      acc[0][0] = __builtin_amdgcn_mfma_f32_16x16x32_bf16(a0, b0, acc[0][0], 0, 0, 0);
      acc[0][1] = __builtin_amdgcn_mfma_f32_16x16x32_bf16(a0, b1, acc[0][1], 0, 0, 0);
      acc[1][0] = __builtin_amdgcn_mfma_f32_16x16x32_bf16(a1, b0, acc[1][0], 0, 0, 0);
      acc[1][1] = __builtin_amdgcn_mfma_f32_16x16x32_bf16(a1, b1, acc[1][1], 0, 0, 0);
    }
    #pragma unroll
    for (int i = 0; i < 2; i++)
      #pragma unroll
      for (int j = 0; j < 2; j++) {
        const int n = wn + j*16 + l16;
        #pragma unroll
        for (int r = 0; r < 4; r++) {
          const int m = i*16 + quad*4 + r;
          xs[m][n] = acc[i][j][r] + x[(size_t)(t0 + m)*DD + n];
        }
      }
  }
  __syncthreads();

  // --- norm1 per row (8 threads/row, 16 elems each) -> hln into Au[., 0:128]
  {
    const int lr = tid >> 3, le = (tid & 7) * 16;
    float vv[16];
    float s = 0.f, sq = 0.f;
    #pragma unroll
    for (int i = 0; i < 16; i++) {
      vv[i] = xs[lr][le + i];
      s += vv[i]; sq += vv[i]*vv[i];
    }
    s += __shfl_xor(s, 1);  s += __shfl_xor(s, 2);  s += __shfl_xor(s, 4);
    sq += __shfl_xor(sq, 1); sq += __shfl_xor(sq, 2); sq += __shfl_xor(sq, 4);
    const float mean = s * (1.f/128.f);
    const float rs = rsqrtf(sq*(1.f/128.f) - mean*mean + 1e-5f);
    #pragma unroll
    for (int g = 0; g < 2; g++) {
      ushort8v p;
      #pragma unroll
      for (int i = 0; i < 8; i++) {
        const int idx = g*8 + i;
        p[i] = f2bf((vv[idx] - mean)*rs*g1[le + idx] + b1[le + idx]);
      }
      *(ushort8v*)&Au[lr][le + g*8] = p;
    }
  }
  // --- stage fc1_w (256x128) -> BigW bf16, stride 136 ---
  {
    const float* wp = fc1_w + (size_t)tid*DD;
    #pragma unroll
    for (int g = 0; g < 16; g++) {
      const float4 v0 = *(const float4*)(wp + g*8);
      const float4 v1 = *(const float4*)(wp + g*8 + 4);
      *(ushort8v*)&BigW[(size_t)tid*136 + g*8] = pack8(v0, v1);
    }
  }
  __syncthreads();

  // --- fc1 MFMA: M=32, N=256, K=128; wave covers 64 n; gelu -> h into Au ---
  {
    const int wn = wave * 64;
    floatx4 acc[2][4] = {};
    #pragma unroll
    for (int ks = 0; ks < 4; ks++) {
      const int ko = ks*32 + quad*8;
      short8 a0 = *(const short8*)&Au[l16][ko];
      short8 a1 = *(const short8*)&Au[16 + l16][ko];
      #pragma unroll
      for (int f = 0; f < 4; f++) {
        short8 bv = *(const short8*)&BigW[(size_t)(wn + f*16 + l16)*136 + ko];
        acc[0][f] = __builtin_amdgcn_mfma_f32_16x16x32_bf16(a0, bv, acc[0][f], 0, 0, 0);
        acc[1][f] = __builtin_amdgcn_mfma_f32_16x16x32_bf16(a1, bv, acc[1][f], 0, 0, 0);
      }
    }
    __syncthreads();   // all hln reads done before Au is overwritten with h
    #pragma unroll
    for (int i = 0; i < 2; i++)
      #pragma unroll
      for (int f = 0; f < 4; f++) {
        const int n = wn + f*16 + l16;
        const float bn = fc1_b[n];
        #pragma unroll
        for (int r = 0; r < 4; r++) {
          const int m = i*16 + quad*4 + r;
          float v = acc[i][f][r] + bn;
          v = 0.5f*v*(1.f + erff(v*0.70710678118f));
          Au[m][n] = f2bf(v);
        }
      }
  }
  // --- stage fc2_w (128x256) -> BigW bf16, stride 264 ---
  {
    const int r = tid >> 1, k0 = (tid & 1) * 128;
    const float* wp = fc2_w + (size_t)r*HH + k0;
    __syncthreads();   // fc1 acc written to Au AND old BigW reads done
    #pragma unroll
    for (int g = 0; g < 16; g++) {
      const float4 v0 = *(const float4*)(wp + g*8);
      const float4 v1 = *(const float4*)(wp + g*8 + 4);
      *(ushort8v*)&BigW[(size_t)r*264 + k0 + g*8] = pack8(v0, v1);
    }
  }
  __syncthreads();

  // --- fc2 MFMA: M=32, N=128, K=256; + bias + xnew residual -> out ---
  {
    const int wn = wave * 32;
    floatx4 acc[2][2] = {};
    #pragma unroll
    for (int ks = 0; ks < 8; ks++) {
      const int ko = ks*32 + quad*8;
      short8 a0 = *(const short8*)&Au[l16][ko];
      short8 a1 = *(const short8*)&Au[16 + l16][ko];
      short8 b0 = *(const short8*)&BigW[(size_t)(wn +      l16)*264 + ko];
      short8 b1 = *(const short8*)&BigW[(size_t)(wn + 16 + l16)*264 + ko];
      acc[0][0] = __builtin_amdgcn_mfma_f32_16x16x32_bf16(a0, b0, acc[0][0], 0, 0, 0);
      acc[0][1] = __builtin_amdgcn_mfma_f32_16x16x32_bf16(a0, b1, acc[0][1], 0, 0, 0);
      acc[1][0] = __builtin_amdgcn_mfma_f32_16x16x32_bf16(a1, b0, acc[1][0], 0, 0, 0);
      acc[1][1] = __builtin_amdgcn_mfma_f32_16x16x32_bf16(a1, b1, acc[1][1], 0, 0, 0);
    }
    #pragma unroll
    for (int i = 0; i < 2; i++)
      #pragma unroll
      for (int j = 0; j < 2; j++) {
        const int n = wn + j*16 + l16;
        const float bn = fc2_b[n];
        #pragma unroll
        for (int r = 0; r < 4; r++) {
          const int m = i*16 + quad*4 + r;
          out[(size_t)(t0 + m)*DD + n] = acc[i][j][r] + bn + xs[m][n];
        }
      }
  }
}

// ---------------------------------------------------------------------------
extern "C" void kernel_launch(void* const* d_in, const int* in_sizes, int n_in,
                              void* d_out, int out_size, void* d_ws, size_t ws_size,
                              hipStream_t stream) {
  const float* x      = (const float*)d_in[0];
  const float* n1g    = (const float*)d_in[1];
  const float* n1b    = (const float*)d_in[2];
  const float* ing    = (const float*)d_in[3];
  const float* inb    = (const float*)d_in[4];
  const float* in_w   = (const float*)d_in[5];
  const float* conv_w = (const float*)d_in[6];
  const float* conv_b = (const float*)d_in[7];
  const float* xproj_w= (const float*)d_in[8];
  const float* dt_w   = (const float*)d_in[9];
  const float* dt_b   = (const float*)d_in[10];
  const float* A_log  = (const float*)d_in[11];
  const float* Dpv    = (const float*)d_in[12];
  const float* out_w  = (const float*)d_in[13];
  const float* fc1_w  = (const float*)d_in[14];
  const float* fc1_b  = (const float*)d_in[15];
  const float* fc2_w  = (const float*)d_in[16];
  const float* fc2_b  = (const float*)d_in[17];
  float* out = (float*)d_out;

  // Workspace layout (~37 MB)
  float* ws    = (float*)d_ws;
  float* xz    = ws;                          // [NT,512]
  float* uc    = xz    + (size_t)NT*2*ED;     // [NT,256]
  float* dbc   = uc    + (size_t)NT*ED;       // [NT,40]
  float* delta = dbc   + (size_t)NT*40;       // [NT,256]
  float* cAP   = delta + (size_t)NT*ED;       // [NC,B,ED,N]
  float* cH    = cAP   + (size_t)NC*BB*ED*NN;

  // 1) xz = LN2(LN1(x)) @ in_w^T   (LN + weight-convert fused)
  gemm_inln_k<<<dim3(512/64, NT/64), 256, 0, stream>>>(x, n1g, n1b, ing, inb, in_w, xz);
  // 2) conv+silu -> xproj(MFMA) -> delta -> chunk summaries
  scan1f_k<<<dim3(2, NC, BB), 256, 0, stream>>>(xz, conv_w, conv_b, xproj_w, dt_w, dt_b,
                                                A_log, uc, dbc, delta, cAP, cH);
  // 3) inter-chunk prefix
  scan2_k<<<(BB*ED*NN)/256, 256, 0, stream>>>(cAP, cH);
  // 4) scan replay + gate + out_proj + LN + MLP + residuals -> out
  tail_k<<<dim3(NC, BB), 256, 0, stream>>>(xz, delta, uc, dbc, cAP, A_log, Dpv,
                                           x, n1g, n1b, out_w, fc1_w, fc1_b,
                                           fc2_w, fc2_b, out);
}